// Round 3
// baseline (226.707 us; speedup 1.0000x reference)
//
#include <hip/hip_runtime.h>
#include <math.h>

#define EDIM 1024
#define NH   16
#define HD   64
#define BATCH 2
#define SEQ  2048
#define NROW (BATCH*SEQ)   // 4096
#define YAT_EPS 0.1f

typedef _Float16 f16;
typedef _Float16 f16x8 __attribute__((ext_vector_type(8)));
typedef _Float16 f16x4 __attribute__((ext_vector_type(4)));
typedef __fp16   h16x2 __attribute__((ext_vector_type(2)));   // cvt_pkrtz native type
typedef float    f32x4 __attribute__((ext_vector_type(4)));

static __device__ __forceinline__ int pk2(float a, float b) {
    union { h16x2 h; int i; } u;
    u.h = __builtin_amdgcn_cvt_pkrtz(a, b);
    return u.i;
}

// ---------------------------------------------------------------------------
// prep kernel (unchanged):
// z<4 : W_z [1024 k][1024 n] fp32 -> Wt_z [n][k] f16 (32x32 LDS transpose)
// z==4: x fp32 -> f16 flat cast (4096 f32 per block)
// ---------------------------------------------------------------------------
__global__ __launch_bounds__(256)
void prep_kernel(const float* __restrict__ x, f16* __restrict__ xb,
                 const float* __restrict__ W0, const float* __restrict__ W1,
                 const float* __restrict__ W2, const float* __restrict__ W3,
                 f16* __restrict__ T0, f16* __restrict__ T1,
                 f16* __restrict__ T2, f16* __restrict__ T3)
{
    const int z = blockIdx.z;
    if (z == 4) {
        const int bid = blockIdx.y * 32 + blockIdx.x;
#pragma unroll
        for (int i = 0; i < 4; ++i) {
            const int off = bid * 4096 + i * 1024 + threadIdx.x * 4;
            const float4 v = *(const float4*)(x + off);
            union { int i2[2]; f16x4 h; } o;
            o.i2[0] = pk2(v.x, v.y);
            o.i2[1] = pk2(v.z, v.w);
            *(f16x4*)(xb + off) = o.h;
        }
        return;
    }
    const float* W = (z == 0) ? W0 : (z == 1) ? W1 : (z == 2) ? W2 : W3;
    f16*         Wt = (z == 0) ? T0 : (z == 1) ? T1 : (z == 2) ? T2 : T3;

    __shared__ float T[32][33];
    const int t = threadIdx.x;
    const int r = t >> 3, c4 = (t & 7) * 4;
    const int bi = blockIdx.x * 32, bj = blockIdx.y * 32;
    const float4 v = *(const float4*)(W + (size_t)(bi + r) * 1024 + bj + c4);
    T[r][c4 + 0] = v.x; T[r][c4 + 1] = v.y; T[r][c4 + 2] = v.z; T[r][c4 + 3] = v.w;
    __syncthreads();
    f16x4 o = {(f16)T[c4 + 0][r], (f16)T[c4 + 1][r], (f16)T[c4 + 2][r], (f16)T[c4 + 3][r]};
    *(f16x4*)(Wt + (size_t)(bj + r) * 1024 + bi + c4) = o;
}

// ---------------------------------------------------------------------------
// MFMA GEMM (unchanged from round 12): template<BM, BN, WM>, WN = 2 fixed.
//   QKV:     <128,128,4> -> 512 thr, 8 waves, 768 blocks = 3/CU.
//   outproj: < 64,128,2> -> 256 thr, 4 waves, 512 blocks = 2/CU.
// epi: 0 = fp32 [M,N]; 1 = l2norm f16 [b,h,s,d]; 2 = f16 [b,h,d,s].
// ---------------------------------------------------------------------------
template<int BM, int BN, int WM>
__global__ __launch_bounds__(WM * 128, 3)
void gemm_f16(const f16* __restrict__ A,
              const f16* __restrict__ B0, const f16* __restrict__ B1, const f16* __restrict__ B2,
              const float* __restrict__ bi0, const float* __restrict__ bi1, const float* __restrict__ bi2,
              void* __restrict__ o0, void* __restrict__ o1, void* __restrict__ o2,
              int e0, int e1, int e2)
{
    constexpr int NT    = WM * 128;
    constexpr int SR    = NT / 4;          // rows staged per pass
    constexpr int ASL   = BM / SR;
    constexpr int BSL   = BN / SR;
    constexpr int ABUF  = BM * 32;
    constexpr int BBUF  = BN * 32;
    constexpr int WROWS = BM / WM;
    constexpr int MT    = WROWS / 16;
    constexpr int HALVES = BN / 128;       // 128-col output halves in epi 1/2
    constexpr int SCH    = 2048 / NT;      // LDS-drain iters per half
    __shared__ __align__(16) char lds[2 * (ABUF + BBUF) * 2];
    f16* As = (f16*)lds;
    f16* Bs = (f16*)lds + 2 * ABUF;

    const int z = blockIdx.z;
    const f16*   Bt   = (z == 0) ? B0  : (z == 1) ? B1  : B2;
    const float* bias = (z == 0) ? bi0 : (z == 1) ? bi1 : bi2;
    void*        Cout = (z == 0) ? o0  : (z == 1) ? o1  : o2;
    const int    epi  = (z == 0) ? e0  : (z == 1) ? e1  : e2;

    const int tid  = threadIdx.x;
    const int lane = tid & 63;
    const int w    = tid >> 6;
    const int cl   = lane & 15;
    const int quad = lane >> 4;
    const int wm = w % WM, wn = w / WM;    // WN = 2
    const int bm = blockIdx.x * BM, bn = blockIdx.y * BN;
    const int wmoff = wm * WROWS;

    const int srow = tid >> 2;
    const int sc   = tid & 3;
    const int ssw  = (sc ^ (srow & 3)) * 8;
    const f16* gA = A  + (size_t)(bm + srow) * 1024 + sc * 8;
    const f16* gB = Bt + (size_t)(bn + srow) * 1024 + sc * 8;
    int lAo[ASL], lBo[BSL];
#pragma unroll
    for (int i = 0; i < ASL; ++i) lAo[i] = (srow + i * SR) * 32 + ssw;
#pragma unroll
    for (int i = 0; i < BSL; ++i) lBo[i] = (srow + i * SR) * 32 + ssw;

    f32x4 acc[MT][4];
#pragma unroll
    for (int i = 0; i < MT; ++i)
#pragma unroll
        for (int j = 0; j < 4; ++j) acc[i][j] = (f32x4){0.f, 0.f, 0.f, 0.f};

    f16x8 ra[ASL], rb[BSL];

#pragma unroll
    for (int i = 0; i < ASL; ++i) ra[i] = *(const f16x8*)(gA + (size_t)i * SR * 1024);
#pragma unroll
    for (int i = 0; i < BSL; ++i) rb[i] = *(const f16x8*)(gB + (size_t)i * SR * 1024);
#pragma unroll
    for (int i = 0; i < ASL; ++i) *(f16x8*)(As + lAo[i]) = ra[i];
#pragma unroll
    for (int i = 0; i < BSL; ++i) *(f16x8*)(Bs + lBo[i]) = rb[i];
#pragma unroll
    for (int i = 0; i < ASL; ++i) ra[i] = *(const f16x8*)(gA + (size_t)i * SR * 1024 + 32);
#pragma unroll
    for (int i = 0; i < BSL; ++i) rb[i] = *(const f16x8*)(gB + (size_t)i * SR * 1024 + 32);
    __syncthreads();

    const int fsw = (quad ^ (cl & 3)) * 8;

    for (int it = 0; it < 32; ++it) {
        const int buf = it & 1, nb = buf ^ 1;
        if (it < 31) {
#pragma unroll
            for (int i = 0; i < ASL; ++i) *(f16x8*)(As + nb * ABUF + lAo[i]) = ra[i];
#pragma unroll
            for (int i = 0; i < BSL; ++i) *(f16x8*)(Bs + nb * BBUF + lBo[i]) = rb[i];
        }
        if (it < 30) {
            const int kn = (it + 2) * 32;
#pragma unroll
            for (int i = 0; i < ASL; ++i) ra[i] = *(const f16x8*)(gA + (size_t)i * SR * 1024 + kn);
#pragma unroll
            for (int i = 0; i < BSL; ++i) rb[i] = *(const f16x8*)(gB + (size_t)i * SR * 1024 + kn);
        }
        f16x8 af[MT], bf[4];
#pragma unroll
        for (int mt = 0; mt < MT; ++mt)
            af[mt] = *(const f16x8*)(&As[buf * ABUF + (wmoff + mt * 16 + cl) * 32 + fsw]);
#pragma unroll
        for (int nt = 0; nt < 4; ++nt)
            bf[nt] = *(const f16x8*)(&Bs[buf * BBUF + (wn * 64 + nt * 16 + cl) * 32 + fsw]);
#pragma unroll
        for (int mt = 0; mt < MT; ++mt)
#pragma unroll
            for (int nt = 0; nt < 4; ++nt)
                acc[mt][nt] = __builtin_amdgcn_mfma_f32_16x16x32_f16(af[mt], bf[nt], acc[mt][nt], 0, 0, 0);
        __syncthreads();
    }

    float bcol[4];
#pragma unroll
    for (int nt = 0; nt < 4; ++nt) bcol[nt] = bias[bn + wn * 64 + nt * 16 + cl];
#pragma unroll
    for (int mt = 0; mt < MT; ++mt)
#pragma unroll
        for (int nt = 0; nt < 4; ++nt)
#pragma unroll
            for (int rg = 0; rg < 4; ++rg) acc[mt][nt][rg] += bcol[nt];

    const int b_idx = bm >> 11, sl0 = bm & (SEQ - 1), h0 = bn >> 6;

    if (epi == 0) {
        float* C = (float*)Cout;
#pragma unroll
        for (int mt = 0; mt < MT; ++mt)
#pragma unroll
            for (int rg = 0; rg < 4; ++rg) {
                const int row = bm + wmoff + mt * 16 + quad * 4 + rg;
#pragma unroll
                for (int nt = 0; nt < 4; ++nt)
                    C[(size_t)row * EDIM + bn + wn * 64 + nt * 16 + cl] = acc[mt][nt][rg];
            }
    } else if (epi == 1) {                // l2norm -> f16 [b,h,s,d]
        if constexpr (BM == 128) {
        f16* C = (f16*)Cout;
        f16* S = (f16*)lds;
#pragma unroll
        for (int h = 0; h < HALVES; ++h) {
            __syncthreads();
            if ((wn >> 1) == h) {
#pragma unroll
                for (int mt = 0; mt < MT; ++mt)
#pragma unroll
                    for (int rg = 0; rg < 4; ++rg) {
                        float ss = 0.f;
#pragma unroll
                        for (int nt = 0; nt < 4; ++nt) ss += acc[mt][nt][rg] * acc[mt][nt][rg];
                        ss += __shfl_xor(ss, 1); ss += __shfl_xor(ss, 2);
                        ss += __shfl_xor(ss, 4); ss += __shfl_xor(ss, 8);
                        const float inv = 1.0f / (sqrtf(ss) + 1e-8f);
                        const int row = wmoff + mt * 16 + quad * 4 + rg;
#pragma unroll
                        for (int nt = 0; nt < 4; ++nt) {
                            const int colh = (wn & 1) * 64 + nt * 16 + cl;
                            S[row * 128 + (((colh >> 3) ^ (row & 15)) * 8) + (colh & 7)] =
                                (f16)(acc[mt][nt][rg] * inv);
                        }
                    }
            }
            __syncthreads();
#pragma unroll
            for (int i = 0; i < SCH; ++i) {
                const int c = tid + i * NT;
                const int s = c >> 4, gi = c & 15;
                f16x8 v = *(const f16x8*)(&S[s * 128 + ((gi ^ (s & 15)) * 8)]);
                const int head = h0 + h * 2 + (gi >> 3), d8 = (gi & 7) * 8;
                *(f16x8*)(C + ((size_t)(b_idx * NH + head) * SEQ + sl0 + s) * HD + d8) = v;
            }
        }
        }
    } else {                              // epi==2: f16 transposed [b,h,d,s]
        if constexpr (BM == 128) {
        f16* C = (f16*)Cout;
        f16* S = (f16*)lds;
#pragma unroll
        for (int h = 0; h < HALVES; ++h) {
            __syncthreads();
            if ((wn >> 1) == h) {
#pragma unroll
                for (int mt = 0; mt < MT; ++mt) {
                    const int s0 = wmoff + mt * 16 + quad * 4;
#pragma unroll
                    for (int nt = 0; nt < 4; ++nt) {
                        const int colh = (wn & 1) * 64 + nt * 16 + cl;
                        f16x4 o = {(f16)acc[mt][nt][0], (f16)acc[mt][nt][1],
                                   (f16)acc[mt][nt][2], (f16)acc[mt][nt][3]};
                        *(f16x4*)(&S[colh * 128 + (((s0 >> 3) ^ (colh & 15)) * 8) + (s0 & 7)]) = o;
                    }
                }
            }
            __syncthreads();
#pragma unroll
            for (int i = 0; i < SCH; ++i) {
                const int c = tid + i * NT;
                const int colh = c >> 4, gi = c & 15;
                f16x8 v = *(const f16x8*)(&S[colh * 128 + ((gi ^ (colh & 15)) * 8)]);
                const int head = h0 + h * 2 + (colh >> 6), d = colh & 63;
                *(f16x8*)(C + ((size_t)(b_idx * NH + head) * HD + d) * SEQ + sl0 + gi * 8) = v;
            }
        }
        }
    }
}

// ---------------------------------------------------------------------------
// Yat attention, round 13: back to 128-q / 512-thread (8 waves = 4 wm x 2 wk),
// but KVBLK=128 pair-tiles -> 16 barriers instead of 32 (work-per-barrier 2x).
// Q fragments load straight from global to regs (no Qs LDS, no preamble
// barrier); freed LDS holds the doubled K/V dbuf: exactly 64 KB -> 2 blk/CU.
// Per-kt interleave (S-MFMA -> score VALU -> PV-MFMA per 16-k slice) keeps
// VGPR <= 128 so __launch_bounds__(512,4) holds 16 waves/CU. setprio(1)
// around MFMA bursts (T5, +4-7% attn measured).
// ---------------------------------------------------------------------------
__global__ __launch_bounds__(512, 4)
void yat_attn(const f16* __restrict__ Qh, const f16* __restrict__ Kh,
              const f16* __restrict__ Vt, f16* __restrict__ AO)
{
    __shared__ __align__(16) char lds[65536];
    f16* KB = (f16*)lds;                    // 2 bufs x (128 x 64) f16
    f16* VB = (f16*)(lds + 32768);          // 2 bufs x (64 x 128) f16

    const int tid  = threadIdx.x;
    const int lane = tid & 63;
    const int w    = tid >> 6;              // 0..7
    const int cl   = lane & 15;
    const int quad = lane >> 4;
    const int wm = w & 3;                   // q quarter (32 q)
    const int wk = w >> 2;                  // k half (64 k of 128)
    const int q0 = blockIdx.x * 128;
    const int bh = blockIdx.y;

    const f16* Qg = Qh + (size_t)bh * SEQ * HD;
    const f16* Kg = Kh + (size_t)bh * SEQ * HD;
    const f16* Vg = Vt + (size_t)bh * HD * SEQ;

    // K staging: 128 rows x 8 groups, 512 thr -> 2 slots each
    const int rk = tid >> 3;                // 0..63 (+64)
    const int gk = tid & 7;
    const f16* gK = Kg + (size_t)rk * HD + gk * 8;
    const int kOff = rk * 64 + ((gk ^ (rk & 7)) * 8);        // +4096 for rows 64..127
    // V staging: 64 rows x 16 groups, 2 slots each
    const int rv = tid >> 4;                // 0..31 (+32)
    const int gv = tid & 15;
    const f16* gV = Vg + (size_t)rv * SEQ + gv * 8;
    const int vOff = rv * 128 + ((gv ^ (rv & 15)) * 8);      // +4096 for rows 32..63

    f16x8 kr0 = *(const f16x8*)(gK);
    f16x8 kr1 = *(const f16x8*)(gK + 64 * HD);
    f16x8 vr0 = *(const f16x8*)(gV);
    f16x8 vr1 = *(const f16x8*)(gV + (size_t)32 * SEQ);

    // Q fragments direct from global: qf[qt][kb] = Q[q0+wm*32+qt*16+cl][(kb*4+quad)*8..]
    f16x8 qf[2][2];
#pragma unroll
    for (int qt = 0; qt < 2; ++qt)
#pragma unroll
        for (int kb = 0; kb < 2; ++kb)
            qf[qt][kb] = *(const f16x8*)(Qg + (size_t)(q0 + wm * 32 + qt * 16 + cl) * HD +
                                         (kb * 4 + quad) * 8);

    f32x4 O[2][4];
    float rs[2] = {0.f, 0.f};
#pragma unroll
    for (int i = 0; i < 2; ++i)
#pragma unroll
        for (int j = 0; j < 4; ++j) O[i][j] = (f32x4){0.f, 0.f, 0.f, 0.f};

    for (int t = 0; t < 16; ++t) {
        const int buf = t & 1;
        f16* Ks = KB + buf * 8192;
        f16* Vs = VB + buf * 8192;
        *(f16x8*)(Ks + kOff)        = kr0;
        *(f16x8*)(Ks + kOff + 4096) = kr1;
        *(f16x8*)(Vs + vOff)        = vr0;
        *(f16x8*)(Vs + vOff + 4096) = vr1;
        if (t < 15) {
            const f16* nK = gK + (size_t)(t + 1) * 128 * HD;
            const f16* nV = gV + (t + 1) * 128;
            kr0 = *(const f16x8*)(nK);
            kr1 = *(const f16x8*)(nK + 64 * HD);
            vr0 = *(const f16x8*)(nV);
            vr1 = *(const f16x8*)(nV + (size_t)32 * SEQ);
        }
        __syncthreads();                    // lgkm drain; next global loads in flight

        // per-kt slice: S^T (16k x 32q) -> yat scores -> PV, 16 k at a time
#pragma unroll
        for (int kt = 0; kt < 4; ++kt) {
            const int krow = (wk * 64 + kt * 16 + cl) * 64;
            f16x8 a0 = *(const f16x8*)(&Ks[krow + ((quad     ^ (cl & 7)) * 8)]);
            f16x8 a1 = *(const f16x8*)(&Ks[krow + (((4 + quad) ^ (cl & 7)) * 8)]);
            f32x4 s0 = (f32x4){0.f, 0.f, 0.f, 0.f};
            f32x4 s1 = (f32x4){0.f, 0.f, 0.f, 0.f};
            __builtin_amdgcn_s_setprio(1);
            s0 = __builtin_amdgcn_mfma_f32_16x16x32_f16(a0, qf[0][0], s0, 0, 0, 0);
            s0 = __builtin_amdgcn_mfma_f32_16x16x32_f16(a1, qf[0][1], s0, 0, 0, 0);
            s1 = __builtin_amdgcn_mfma_f32_16x16x32_f16(a0, qf[1][0], s1, 0, 0, 0);
            s1 = __builtin_amdgcn_mfma_f32_16x16x32_f16(a1, qf[1][1], s1, 0, 0, 0);
            __builtin_amdgcn_s_setprio(0);

            // yat scores p = 4.41*rcp(u) + u - 4.2, u = 1.1 - d
            f16x4 pa0, pa1;
            {
                float p0[4], p1[4];
#pragma unroll
                for (int rg = 0; rg < 4; ++rg) {
                    const float u0 = (1.0f + YAT_EPS) - s0[rg];
                    const float u1 = (1.0f + YAT_EPS) - s1[rg];
                    p0[rg] = fmaf(4.41f, __builtin_amdgcn_rcpf(u0), u0 - 4.2f);
                    p1[rg] = fmaf(4.41f, __builtin_amdgcn_rcpf(u1), u1 - 4.2f);
                    rs[0] += p0[rg];
                    rs[1] += p1[rg];
                }
                union { int i2[2]; f16x4 h; } pk_;
                pk_.i2[0] = pk2(p0[0], p0[1]); pk_.i2[1] = pk2(p0[2], p0[3]);
                pa0 = pk_.h;
                pk_.i2[0] = pk2(p1[0], p1[1]); pk_.i2[1] = pk2(p1[2], p1[3]);
                pa1 = pk_.h;
            }

            // PV: k window = wk*64 + kt*16 + quad*4 + j
            const int g = wk * 8 + kt * 2 + (quad >> 1);
            __builtin_amdgcn_s_setprio(1);
#pragma unroll
            for (int dn = 0; dn < 4; ++dn) {
                const int row = dn * 16 + cl;
                f16x4 vb = *(const f16x4*)(&Vs[row * 128 + ((g ^ (row & 15)) * 8) + (quad & 1) * 4]);
                O[0][dn] = __builtin_amdgcn_mfma_f32_16x16x16f16(pa0, vb, O[0][dn], 0, 0, 0);
                O[1][dn] = __builtin_amdgcn_mfma_f32_16x16x16f16(pa1, vb, O[1][dn], 0, 0, 0);
            }
            __builtin_amdgcn_s_setprio(0);
        }
        __syncthreads();                    // all reads done before next overwrite
    }

    // ---- epilogue: cross-wk reduce rs and O, normalize, store ----
    float* rs_s = (float*)lds;              // 2 x 128 floats
    float* Ox   = (float*)(lds + 1024);     // 128 x 64 floats

#pragma unroll
    for (int qt = 0; qt < 2; ++qt) {
        float t = rs[qt];
        t += __shfl_xor(t, 16);
        t += __shfl_xor(t, 32);
        if (quad == 0) rs_s[wk * 128 + wm * 32 + qt * 16 + cl] = t;
    }
    if (wk == 1) {
#pragma unroll
        for (int qt = 0; qt < 2; ++qt)
#pragma unroll
            for (int dn = 0; dn < 4; ++dn)
#pragma unroll
                for (int rg = 0; rg < 4; ++rg)
                    Ox[(wm * 32 + qt * 16 + quad * 4 + rg) * 64 + dn * 16 + cl] = O[qt][dn][rg];
    }
    __syncthreads();
    if (wk == 0) {
        const int b = bh >> 4, h = bh & 15;
#pragma unroll
        for (int qt = 0; qt < 2; ++qt)
#pragma unroll
            for (int rg = 0; rg < 4; ++rg) {
                const int ql = wm * 32 + qt * 16 + quad * 4 + rg;
                const float tot = rs_s[ql] + rs_s[128 + ql];
                const float inv = 1.0f / (tot + 1e-6f);
                const size_t rowoff = ((size_t)b * SEQ + q0 + ql) * EDIM + h * 64;
#pragma unroll
                for (int dn = 0; dn < 4; ++dn)
                    AO[rowoff + dn * 16 + cl] =
                        (f16)((O[qt][dn][rg] + Ox[ql * 64 + dn * 16 + cl]) * inv);
            }
    }
}

// ---------------------------------------------------------------------------
extern "C" void kernel_launch(void* const* d_in, const int* in_sizes, int n_in,
                              void* d_out, int out_size, void* d_ws, size_t ws_size,
                              hipStream_t stream)
{
    const float* x  = (const float*)d_in[0];
    const float* Wq = (const float*)d_in[1];
    const float* bq = (const float*)d_in[2];
    const float* Wk = (const float*)d_in[3];
    const float* bk = (const float*)d_in[4];
    const float* Wv = (const float*)d_in[5];
    const float* bv = (const float*)d_in[6];
    const float* Wo = (const float*)d_in[7];
    const float* bo = (const float*)d_in[8];

    char* p = (char*)d_ws;
    f16* xb  = (f16*)p;                 p += (size_t)NROW * EDIM * 2;   // 8 MB
    f16* Wqt = (f16*)p;                 p += (size_t)EDIM * EDIM * 2;   // 2 MB
    f16* Wkt = (f16*)p;                 p += (size_t)EDIM * EDIM * 2;
    f16* Wvt = (f16*)p;                 p += (size_t)EDIM * EDIM * 2;
    f16* Wot = (f16*)p;                 p += (size_t)EDIM * EDIM * 2;
    f16* Qhb = (f16*)p;                 p += (size_t)NROW * EDIM * 2;   // [b,h,s,d]
    f16* Khb = (f16*)p;                 p += (size_t)NROW * EDIM * 2;
    f16* Vtb = (f16*)p;                 p += (size_t)NROW * EDIM * 2;   // [b,h,d,s]
    f16* AOb = (f16*)p;                 p += (size_t)NROW * EDIM * 2;   // [b,s,e]

    // prep: weight transposes (z 0..3) + x cast (z 4) in one launch
    prep_kernel<<<dim3(32, 32, 5), 256, 0, stream>>>(x, xb, Wq, Wk, Wv, Wo,
                                                     Wqt, Wkt, Wvt, Wot);

    // fused Q/K/V projections: 128x128 tiles, 8 waves -> 768 blocks
    gemm_f16<128, 128, 4><<<dim3(NROW / 128, EDIM / 128, 3), 512, 0, stream>>>(
        xb, Wqt, Wkt, Wvt, bq, bk, bv, Qhb, Khb, Vtb, 1, 1, 2);

    // attention: 128-q tiles, 128-k pair-tiles -> 512 blocks, 16 barriers
    yat_attn<<<dim3(SEQ / 128, BATCH * NH), 512, 0, stream>>>(Qhb, Khb, Vtb, AOb);

    // output projection: 64x128 tiles -> 512 blocks
    gemm_f16<64, 128, 2><<<dim3(NROW / 64, EDIM / 128, 1), 256, 0, stream>>>(
        AOb, Wot, Wot, Wot, bo, bo, bo, d_out, d_out, d_out, 0, 0, 0);
}

// Round 4
// 199.298 us; speedup vs baseline: 1.1375x; 1.1375x over previous
//
#include <hip/hip_runtime.h>
#include <math.h>

#define EDIM 1024
#define NH   16
#define HD   64
#define BATCH 2
#define SEQ  2048
#define NROW (BATCH*SEQ)   // 4096
#define YAT_EPS 0.1f

typedef _Float16 f16;
typedef _Float16 f16x8 __attribute__((ext_vector_type(8)));
typedef _Float16 f16x4 __attribute__((ext_vector_type(4)));
typedef __fp16   h16x2 __attribute__((ext_vector_type(2)));   // cvt_pkrtz native type
typedef float    f32x4 __attribute__((ext_vector_type(4)));
typedef float    f32x2 __attribute__((ext_vector_type(2)));

static __device__ __forceinline__ int pk2(float a, float b) {
    union { h16x2 h; int i; } u;
    u.h = __builtin_amdgcn_cvt_pkrtz(a, b);
    return u.i;
}

// packed dual-f32 VALU (VOP3P) — compiler never auto-emits these
static __device__ __forceinline__ f32x2 pk_fma(f32x2 a, f32x2 b, f32x2 c) {
    f32x2 d;
    asm("v_pk_fma_f32 %0, %1, %2, %3" : "=v"(d) : "v"(a), "v"(b), "v"(c));
    return d;
}
static __device__ __forceinline__ f32x2 pk_add(f32x2 a, f32x2 b) {
    f32x2 d;
    asm("v_pk_add_f32 %0, %1, %2" : "=v"(d) : "v"(a), "v"(b));
    return d;
}

// ---------------------------------------------------------------------------
// prep kernel (unchanged):
// z<4 : W_z [1024 k][1024 n] fp32 -> Wt_z [n][k] f16 (32x32 LDS transpose)
// z==4: x fp32 -> f16 flat cast (4096 f32 per block)
// ---------------------------------------------------------------------------
__global__ __launch_bounds__(256)
void prep_kernel(const float* __restrict__ x, f16* __restrict__ xb,
                 const float* __restrict__ W0, const float* __restrict__ W1,
                 const float* __restrict__ W2, const float* __restrict__ W3,
                 f16* __restrict__ T0, f16* __restrict__ T1,
                 f16* __restrict__ T2, f16* __restrict__ T3)
{
    const int z = blockIdx.z;
    if (z == 4) {
        const int bid = blockIdx.y * 32 + blockIdx.x;
#pragma unroll
        for (int i = 0; i < 4; ++i) {
            const int off = bid * 4096 + i * 1024 + threadIdx.x * 4;
            const float4 v = *(const float4*)(x + off);
            union { int i2[2]; f16x4 h; } o;
            o.i2[0] = pk2(v.x, v.y);
            o.i2[1] = pk2(v.z, v.w);
            *(f16x4*)(xb + off) = o.h;
        }
        return;
    }
    const float* W = (z == 0) ? W0 : (z == 1) ? W1 : (z == 2) ? W2 : W3;
    f16*         Wt = (z == 0) ? T0 : (z == 1) ? T1 : (z == 2) ? T2 : T3;

    __shared__ float T[32][33];
    const int t = threadIdx.x;
    const int r = t >> 3, c4 = (t & 7) * 4;
    const int bi = blockIdx.x * 32, bj = blockIdx.y * 32;
    const float4 v = *(const float4*)(W + (size_t)(bi + r) * 1024 + bj + c4);
    T[r][c4 + 0] = v.x; T[r][c4 + 1] = v.y; T[r][c4 + 2] = v.z; T[r][c4 + 3] = v.w;
    __syncthreads();
    f16x4 o = {(f16)T[c4 + 0][r], (f16)T[c4 + 1][r], (f16)T[c4 + 2][r], (f16)T[c4 + 3][r]};
    *(f16x4*)(Wt + (size_t)(bj + r) * 1024 + bi + c4) = o;
}

// ---------------------------------------------------------------------------
// MFMA GEMM (unchanged from round 12): template<BM, BN, WM>, WN = 2 fixed.
//   QKV:     <128,128,4> -> 512 thr, 8 waves, 768 blocks = 3/CU.
//   outproj: < 64,128,2> -> 256 thr, 4 waves, 512 blocks = 2/CU.
// epi: 0 = fp32 [M,N]; 1 = l2norm f16 [b,h,s,d]; 2 = f16 [b,h,d,s].
// ---------------------------------------------------------------------------
template<int BM, int BN, int WM>
__global__ __launch_bounds__(WM * 128, 3)
void gemm_f16(const f16* __restrict__ A,
              const f16* __restrict__ B0, const f16* __restrict__ B1, const f16* __restrict__ B2,
              const float* __restrict__ bi0, const float* __restrict__ bi1, const float* __restrict__ bi2,
              void* __restrict__ o0, void* __restrict__ o1, void* __restrict__ o2,
              int e0, int e1, int e2)
{
    constexpr int NT    = WM * 128;
    constexpr int SR    = NT / 4;          // rows staged per pass
    constexpr int ASL   = BM / SR;
    constexpr int BSL   = BN / SR;
    constexpr int ABUF  = BM * 32;
    constexpr int BBUF  = BN * 32;
    constexpr int WROWS = BM / WM;
    constexpr int MT    = WROWS / 16;
    constexpr int HALVES = BN / 128;       // 128-col output halves in epi 1/2
    constexpr int SCH    = 2048 / NT;      // LDS-drain iters per half
    __shared__ __align__(16) char lds[2 * (ABUF + BBUF) * 2];
    f16* As = (f16*)lds;
    f16* Bs = (f16*)lds + 2 * ABUF;

    const int z = blockIdx.z;
    const f16*   Bt   = (z == 0) ? B0  : (z == 1) ? B1  : B2;
    const float* bias = (z == 0) ? bi0 : (z == 1) ? bi1 : bi2;
    void*        Cout = (z == 0) ? o0  : (z == 1) ? o1  : o2;
    const int    epi  = (z == 0) ? e0  : (z == 1) ? e1  : e2;

    const int tid  = threadIdx.x;
    const int lane = tid & 63;
    const int w    = tid >> 6;
    const int cl   = lane & 15;
    const int quad = lane >> 4;
    const int wm = w % WM, wn = w / WM;    // WN = 2
    const int bm = blockIdx.x * BM, bn = blockIdx.y * BN;
    const int wmoff = wm * WROWS;

    const int srow = tid >> 2;
    const int sc   = tid & 3;
    const int ssw  = (sc ^ (srow & 3)) * 8;
    const f16* gA = A  + (size_t)(bm + srow) * 1024 + sc * 8;
    const f16* gB = Bt + (size_t)(bn + srow) * 1024 + sc * 8;
    int lAo[ASL], lBo[BSL];
#pragma unroll
    for (int i = 0; i < ASL; ++i) lAo[i] = (srow + i * SR) * 32 + ssw;
#pragma unroll
    for (int i = 0; i < BSL; ++i) lBo[i] = (srow + i * SR) * 32 + ssw;

    f32x4 acc[MT][4];
#pragma unroll
    for (int i = 0; i < MT; ++i)
#pragma unroll
        for (int j = 0; j < 4; ++j) acc[i][j] = (f32x4){0.f, 0.f, 0.f, 0.f};

    f16x8 ra[ASL], rb[BSL];

#pragma unroll
    for (int i = 0; i < ASL; ++i) ra[i] = *(const f16x8*)(gA + (size_t)i * SR * 1024);
#pragma unroll
    for (int i = 0; i < BSL; ++i) rb[i] = *(const f16x8*)(gB + (size_t)i * SR * 1024);
#pragma unroll
    for (int i = 0; i < ASL; ++i) *(f16x8*)(As + lAo[i]) = ra[i];
#pragma unroll
    for (int i = 0; i < BSL; ++i) *(f16x8*)(Bs + lBo[i]) = rb[i];
#pragma unroll
    for (int i = 0; i < ASL; ++i) ra[i] = *(const f16x8*)(gA + (size_t)i * SR * 1024 + 32);
#pragma unroll
    for (int i = 0; i < BSL; ++i) rb[i] = *(const f16x8*)(gB + (size_t)i * SR * 1024 + 32);
    __syncthreads();

    const int fsw = (quad ^ (cl & 3)) * 8;

    for (int it = 0; it < 32; ++it) {
        const int buf = it & 1, nb = buf ^ 1;
        if (it < 31) {
#pragma unroll
            for (int i = 0; i < ASL; ++i) *(f16x8*)(As + nb * ABUF + lAo[i]) = ra[i];
#pragma unroll
            for (int i = 0; i < BSL; ++i) *(f16x8*)(Bs + nb * BBUF + lBo[i]) = rb[i];
        }
        if (it < 30) {
            const int kn = (it + 2) * 32;
#pragma unroll
            for (int i = 0; i < ASL; ++i) ra[i] = *(const f16x8*)(gA + (size_t)i * SR * 1024 + kn);
#pragma unroll
            for (int i = 0; i < BSL; ++i) rb[i] = *(const f16x8*)(gB + (size_t)i * SR * 1024 + kn);
        }
        f16x8 af[MT], bf[4];
#pragma unroll
        for (int mt = 0; mt < MT; ++mt)
            af[mt] = *(const f16x8*)(&As[buf * ABUF + (wmoff + mt * 16 + cl) * 32 + fsw]);
#pragma unroll
        for (int nt = 0; nt < 4; ++nt)
            bf[nt] = *(const f16x8*)(&Bs[buf * BBUF + (wn * 64 + nt * 16 + cl) * 32 + fsw]);
#pragma unroll
        for (int mt = 0; mt < MT; ++mt)
#pragma unroll
            for (int nt = 0; nt < 4; ++nt)
                acc[mt][nt] = __builtin_amdgcn_mfma_f32_16x16x32_f16(af[mt], bf[nt], acc[mt][nt], 0, 0, 0);
        __syncthreads();
    }

    float bcol[4];
#pragma unroll
    for (int nt = 0; nt < 4; ++nt) bcol[nt] = bias[bn + wn * 64 + nt * 16 + cl];
#pragma unroll
    for (int mt = 0; mt < MT; ++mt)
#pragma unroll
        for (int nt = 0; nt < 4; ++nt)
#pragma unroll
            for (int rg = 0; rg < 4; ++rg) acc[mt][nt][rg] += bcol[nt];

    const int b_idx = bm >> 11, sl0 = bm & (SEQ - 1), h0 = bn >> 6;

    if (epi == 0) {
        float* C = (float*)Cout;
#pragma unroll
        for (int mt = 0; mt < MT; ++mt)
#pragma unroll
            for (int rg = 0; rg < 4; ++rg) {
                const int row = bm + wmoff + mt * 16 + quad * 4 + rg;
#pragma unroll
                for (int nt = 0; nt < 4; ++nt)
                    C[(size_t)row * EDIM + bn + wn * 64 + nt * 16 + cl] = acc[mt][nt][rg];
            }
    } else if (epi == 1) {                // l2norm -> f16 [b,h,s,d]
        if constexpr (BM == 128) {
        f16* C = (f16*)Cout;
        f16* S = (f16*)lds;
#pragma unroll
        for (int h = 0; h < HALVES; ++h) {
            __syncthreads();
            if ((wn >> 1) == h) {
#pragma unroll
                for (int mt = 0; mt < MT; ++mt)
#pragma unroll
                    for (int rg = 0; rg < 4; ++rg) {
                        float ss = 0.f;
#pragma unroll
                        for (int nt = 0; nt < 4; ++nt) ss += acc[mt][nt][rg] * acc[mt][nt][rg];
                        ss += __shfl_xor(ss, 1); ss += __shfl_xor(ss, 2);
                        ss += __shfl_xor(ss, 4); ss += __shfl_xor(ss, 8);
                        const float inv = 1.0f / (sqrtf(ss) + 1e-8f);
                        const int row = wmoff + mt * 16 + quad * 4 + rg;
#pragma unroll
                        for (int nt = 0; nt < 4; ++nt) {
                            const int colh = (wn & 1) * 64 + nt * 16 + cl;
                            S[row * 128 + (((colh >> 3) ^ (row & 15)) * 8) + (colh & 7)] =
                                (f16)(acc[mt][nt][rg] * inv);
                        }
                    }
            }
            __syncthreads();
#pragma unroll
            for (int i = 0; i < SCH; ++i) {
                const int c = tid + i * NT;
                const int s = c >> 4, gi = c & 15;
                f16x8 v = *(const f16x8*)(&S[s * 128 + ((gi ^ (s & 15)) * 8)]);
                const int head = h0 + h * 2 + (gi >> 3), d8 = (gi & 7) * 8;
                *(f16x8*)(C + ((size_t)(b_idx * NH + head) * SEQ + sl0 + s) * HD + d8) = v;
            }
        }
        }
    } else {                              // epi==2: f16 transposed [b,h,d,s]
        if constexpr (BM == 128) {
        f16* C = (f16*)Cout;
        f16* S = (f16*)lds;
#pragma unroll
        for (int h = 0; h < HALVES; ++h) {
            __syncthreads();
            if ((wn >> 1) == h) {
#pragma unroll
                for (int mt = 0; mt < MT; ++mt) {
                    const int s0 = wmoff + mt * 16 + quad * 4;
#pragma unroll
                    for (int nt = 0; nt < 4; ++nt) {
                        const int colh = (wn & 1) * 64 + nt * 16 + cl;
                        f16x4 o = {(f16)acc[mt][nt][0], (f16)acc[mt][nt][1],
                                   (f16)acc[mt][nt][2], (f16)acc[mt][nt][3]};
                        *(f16x4*)(&S[colh * 128 + (((s0 >> 3) ^ (colh & 15)) * 8) + (s0 & 7)]) = o;
                    }
                }
            }
            __syncthreads();
#pragma unroll
            for (int i = 0; i < SCH; ++i) {
                const int c = tid + i * NT;
                const int colh = c >> 4, gi = c & 15;
                f16x8 v = *(const f16x8*)(&S[colh * 128 + ((gi ^ (colh & 15)) * 8)]);
                const int head = h0 + h * 2 + (colh >> 6), d = colh & 63;
                *(f16x8*)(C + ((size_t)(b_idx * NH + head) * HD + d) * SEQ + sl0 + gi * 8) = v;
            }
        }
        }
    }
}

// ---------------------------------------------------------------------------
// Yat attention, round 14: round-1 structure restored EXACTLY (59.2 us,
// VGPR 60, no spill), plus two contained changes:
//  (1) score math in packed dual-f32 (v_pk_fma_f32 / v_pk_add_f32): halves
//      the dominant VALU block (scores were ~half of 50% VALUBusy).
//      rs accumulates as packed pairs too; +2 VGPR only -> stays <= 64 cap.
//  (2) s_setprio(1) around the two MFMA clusters (T5, +4-7% attn measured).
// 512 threads (8 waves = 4 wm x 2 wk), 128-q tile, 64-k tiles, 32 iters,
// 1 barrier/iter, LDS 48 KB.
// ---------------------------------------------------------------------------
__global__ __launch_bounds__(512, 4)
void yat_attn(const f16* __restrict__ Qh, const f16* __restrict__ Kh,
              const f16* __restrict__ Vt, f16* __restrict__ AO)
{
    __shared__ __align__(16) char lds[49152];
    f16* Qs = (f16*)lds;                    // 128 x 64
    f16* KB = (f16*)(lds + 16384);          // 2 bufs x 4096 f16
    f16* VB = (f16*)(lds + 32768);          // 2 bufs x 4096 f16

    const int tid  = threadIdx.x;
    const int lane = tid & 63;
    const int w    = tid >> 6;
    const int cl   = lane & 15;
    const int quad = lane >> 4;
    const int wm = w & 3;                   // q quarter (32 q)
    const int wk = w >> 2;                  // k half (32 k)
    const int q0 = blockIdx.x * 128;
    const int bh = blockIdx.y;

    const f16* Qg = Qh + (size_t)bh * SEQ * HD;
    const f16* Kg = Kh + (size_t)bh * SEQ * HD;
    const f16* Vg = Vt + (size_t)bh * HD * SEQ;

    const int rkv = tid >> 3;               // 0..63
    const int gkv = tid & 7;
    const f16* gK = Kg + (size_t)rkv * HD + gkv * 8;
    const f16* gV = Vg + (size_t)rkv * SEQ + gkv * 8;
    const int lkOff = rkv * 64 + ((gkv ^ (rkv & 7)) * 8);

    f16x8 kr = *(const f16x8*)(gK);
    f16x8 vr = *(const f16x8*)(gV);

#pragma unroll
    for (int i = 0; i < 2; ++i) {
        const int s0 = tid + i * 512;
        const int row = s0 >> 3, g = s0 & 7;
        f16x8 v = *(const f16x8*)(Qg + (size_t)(q0 + row) * HD + g * 8);
        *(f16x8*)(&Qs[row * 64 + ((g ^ (row & 7)) * 8)]) = v;
    }
    __syncthreads();
    f16x8 qf[2][2];
#pragma unroll
    for (int qt = 0; qt < 2; ++qt)
#pragma unroll
        for (int kb = 0; kb < 2; ++kb)
            qf[qt][kb] = *(const f16x8*)(&Qs[(wm * 32 + qt * 16 + cl) * 64 +
                                             ((kb * 4 + quad) ^ (cl & 7)) * 8]);

    f32x4 O[2][4];
    f32x2 rs_pk[2];
#pragma unroll
    for (int i = 0; i < 2; ++i) {
        rs_pk[i] = (f32x2){0.f, 0.f};
#pragma unroll
        for (int j = 0; j < 4; ++j) O[i][j] = (f32x4){0.f, 0.f, 0.f, 0.f};
    }

    const f32x2 c_m1  = {-1.0f, -1.0f};
    const f32x2 c_u0  = {1.0f + YAT_EPS, 1.0f + YAT_EPS};
    const f32x2 c_m42 = {-4.2f, -4.2f};
    const f32x2 c_441 = {4.41f, 4.41f};

    for (int t = 0; t < 32; ++t) {
        const int buf = t & 1;
        *(f16x8*)(&KB[buf * 4096 + lkOff]) = kr;
        *(f16x8*)(&VB[buf * 4096 + lkOff]) = vr;
        if (t < 31) {
            kr = *(const f16x8*)(gK + (size_t)(t + 1) * 64 * HD);
            vr = *(const f16x8*)(gV + (t + 1) * 64);
        }
        __syncthreads();                    // lgkm drain; next loads in flight

        const f16* Ks = KB + buf * 4096;
        const f16* Vs = VB + buf * 4096;

        // ---- S^T (32k x 32q) = K.Q^T, K=32 MFMAs ----
        f32x4 s[2][2];
#pragma unroll
        for (int kt = 0; kt < 2; ++kt)
#pragma unroll
            for (int qt = 0; qt < 2; ++qt) s[kt][qt] = (f32x4){0.f, 0.f, 0.f, 0.f};
        __builtin_amdgcn_s_setprio(1);
#pragma unroll
        for (int kb = 0; kb < 2; ++kb) {
            const int sw = ((kb * 4 + quad) ^ (cl & 7)) * 8;
            f16x8 af0 = *(const f16x8*)(&Ks[(wk * 32 +  0 + cl) * 64 + sw]);
            f16x8 af1 = *(const f16x8*)(&Ks[(wk * 32 + 16 + cl) * 64 + sw]);
#pragma unroll
            for (int qt = 0; qt < 2; ++qt) {
                s[0][qt] = __builtin_amdgcn_mfma_f32_16x16x32_f16(af0, qf[qt][kb], s[0][qt], 0, 0, 0);
                s[1][qt] = __builtin_amdgcn_mfma_f32_16x16x32_f16(af1, qf[qt][kb], s[1][qt], 0, 0, 0);
            }
        }
        __builtin_amdgcn_s_setprio(0);

        // ---- yat scores, packed pairs: u = 1.1 - d; p = 4.41*rcp(u) + u - 4.2
        f16x4 pa16[2][2];
#pragma unroll
        for (int kt = 0; kt < 2; ++kt)
#pragma unroll
            for (int qt = 0; qt < 2; ++qt) {
                f32x2 d01 = {s[kt][qt][0], s[kt][qt][1]};
                f32x2 d23 = {s[kt][qt][2], s[kt][qt][3]};
                f32x2 u01 = pk_fma(d01, c_m1, c_u0);
                f32x2 u23 = pk_fma(d23, c_m1, c_u0);
                f32x2 r01 = {__builtin_amdgcn_rcpf(u01[0]), __builtin_amdgcn_rcpf(u01[1])};
                f32x2 r23 = {__builtin_amdgcn_rcpf(u23[0]), __builtin_amdgcn_rcpf(u23[1])};
                f32x2 p01 = pk_fma(c_441, r01, pk_add(u01, c_m42));
                f32x2 p23 = pk_fma(c_441, r23, pk_add(u23, c_m42));
                rs_pk[qt] = pk_add(rs_pk[qt], p01);
                rs_pk[qt] = pk_add(rs_pk[qt], p23);
                union { int i2[2]; f16x4 h; } pk_;
                pk_.i2[0] = pk2(p01[0], p01[1]);
                pk_.i2[1] = pk2(p23[0], p23[1]);
                pa16[kt][qt] = pk_.h;
            }

        // ---- O += P.V via 16x16x16 MFMAs (k window: wk*32 + kt*16) ----
        __builtin_amdgcn_s_setprio(1);
#pragma unroll
        for (int kt = 0; kt < 2; ++kt)
#pragma unroll
            for (int dn = 0; dn < 4; ++dn) {
                const int row = dn * 16 + cl;
                const int g = wk * 4 + kt * 2 + (quad >> 1);
                f16x4 vb = *(const f16x4*)(&Vs[row * 64 + ((g ^ (row & 7)) * 8) + (quad & 1) * 4]);
#pragma unroll
                for (int qt = 0; qt < 2; ++qt)
                    O[qt][dn] = __builtin_amdgcn_mfma_f32_16x16x16f16(pa16[kt][qt], vb, O[qt][dn], 0, 0, 0);
            }
        __builtin_amdgcn_s_setprio(0);
    }

    // ---- epilogue: cross-wk reduce rs and O, normalize, store ----
    __syncthreads();
    float* rs_s = (float*)lds;
    float* Ox   = (float*)(lds + 1024);

#pragma unroll
    for (int qt = 0; qt < 2; ++qt) {
        float t = rs_pk[qt][0] + rs_pk[qt][1];
        t += __shfl_xor(t, 16);
        t += __shfl_xor(t, 32);
        if (quad == 0) rs_s[wk * 128 + wm * 32 + qt * 16 + cl] = t;
    }
    if (wk == 1) {
#pragma unroll
        for (int qt = 0; qt < 2; ++qt)
#pragma unroll
            for (int dn = 0; dn < 4; ++dn)
#pragma unroll
                for (int rg = 0; rg < 4; ++rg)
                    Ox[(wm * 32 + qt * 16 + quad * 4 + rg) * 64 + dn * 16 + cl] = O[qt][dn][rg];
    }
    __syncthreads();
    if (wk == 0) {
        const int b = bh >> 4, h = bh & 15;
#pragma unroll
        for (int qt = 0; qt < 2; ++qt)
#pragma unroll
            for (int rg = 0; rg < 4; ++rg) {
                const int ql = wm * 32 + qt * 16 + quad * 4 + rg;
                const float tot = rs_s[ql] + rs_s[128 + ql];
                const float inv = 1.0f / (tot + 1e-6f);
                const size_t rowoff = ((size_t)b * SEQ + q0 + ql) * EDIM + h * 64;
#pragma unroll
                for (int dn = 0; dn < 4; ++dn)
                    AO[rowoff + dn * 16 + cl] =
                        (f16)((O[qt][dn][rg] + Ox[ql * 64 + dn * 16 + cl]) * inv);
            }
    }
}

// ---------------------------------------------------------------------------
extern "C" void kernel_launch(void* const* d_in, const int* in_sizes, int n_in,
                              void* d_out, int out_size, void* d_ws, size_t ws_size,
                              hipStream_t stream)
{
    const float* x  = (const float*)d_in[0];
    const float* Wq = (const float*)d_in[1];
    const float* bq = (const float*)d_in[2];
    const float* Wk = (const float*)d_in[3];
    const float* bk = (const float*)d_in[4];
    const float* Wv = (const float*)d_in[5];
    const float* bv = (const float*)d_in[6];
    const float* Wo = (const float*)d_in[7];
    const float* bo = (const float*)d_in[8];

    char* p = (char*)d_ws;
    f16* xb  = (f16*)p;                 p += (size_t)NROW * EDIM * 2;   // 8 MB
    f16* Wqt = (f16*)p;                 p += (size_t)EDIM * EDIM * 2;   // 2 MB
    f16* Wkt = (f16*)p;                 p += (size_t)EDIM * EDIM * 2;
    f16* Wvt = (f16*)p;                 p += (size_t)EDIM * EDIM * 2;
    f16* Wot = (f16*)p;                 p += (size_t)EDIM * EDIM * 2;
    f16* Qhb = (f16*)p;                 p += (size_t)NROW * EDIM * 2;   // [b,h,s,d]
    f16* Khb = (f16*)p;                 p += (size_t)NROW * EDIM * 2;
    f16* Vtb = (f16*)p;                 p += (size_t)NROW * EDIM * 2;   // [b,h,d,s]
    f16* AOb = (f16*)p;                 p += (size_t)NROW * EDIM * 2;   // [b,s,e]

    // prep: weight transposes (z 0..3) + x cast (z 4) in one launch
    prep_kernel<<<dim3(32, 32, 5), 256, 0, stream>>>(x, xb, Wq, Wk, Wv, Wo,
                                                     Wqt, Wkt, Wvt, Wot);

    // fused Q/K/V projections: 128x128 tiles, 8 waves -> 768 blocks
    gemm_f16<128, 128, 4><<<dim3(NROW / 128, EDIM / 128, 3), 512, 0, stream>>>(
        xb, Wqt, Wkt, Wvt, bq, bk, bv, Qhb, Khb, Vtb, 1, 1, 2);

    // attention: 128-q tiles, 64-k tiles -> 512 blocks (round-1 structure)
    yat_attn<<<dim3(SEQ / 128, BATCH * NH), 512, 0, stream>>>(Qhb, Khb, Vtb, AOb);

    // output projection: 64x128 tiles -> 512 blocks
    gemm_f16<64, 128, 2><<<dim3(NROW / 64, EDIM / 128, 1), 256, 0, stream>>>(
        AOb, Wot, Wot, Wot, bo, bo, bo, d_out, d_out, d_out, 0, 0, 0);
}

// Round 6
// 193.064 us; speedup vs baseline: 1.1743x; 1.0323x over previous
//
#include <hip/hip_runtime.h>
#include <math.h>

#define EDIM 1024
#define NH   16
#define HD   64
#define BATCH 2
#define SEQ  2048
#define NROW (BATCH*SEQ)   // 4096
#define YAT_EPS 0.1f

typedef _Float16 f16;
typedef _Float16 f16x8 __attribute__((ext_vector_type(8)));
typedef _Float16 f16x4 __attribute__((ext_vector_type(4)));
typedef __fp16   h16x2 __attribute__((ext_vector_type(2)));   // cvt_pkrtz native type
typedef float    f32x4 __attribute__((ext_vector_type(4)));

static __device__ __forceinline__ int pk2(float a, float b) {
    union { h16x2 h; int i; } u;
    u.h = __builtin_amdgcn_cvt_pkrtz(a, b);
    return u.i;
}

// async global->LDS, 16B per lane. LDS dest must be wave-uniform base +
// lane*16 (m104); our staging map (tid>>2)*32+(tid&3)*8 f16 == tid*16 B is
// exactly that. Source carries the swizzle (rule #21 / m173).
static __device__ __forceinline__ void gload16(const f16* g, f16* l) {
    __builtin_amdgcn_global_load_lds(
        (const __attribute__((address_space(1))) void*)g,
        (__attribute__((address_space(3))) void*)l,
        16, 0, 0);
}

// ---------------------------------------------------------------------------
// prep kernel (unchanged):
// z<4 : W_z [1024 k][1024 n] fp32 -> Wt_z [n][k] f16 (32x32 LDS transpose)
// z==4: x fp32 -> f16 flat cast (4096 f32 per block)
// ---------------------------------------------------------------------------
__global__ __launch_bounds__(256)
void prep_kernel(const float* __restrict__ x, f16* __restrict__ xb,
                 const float* __restrict__ W0, const float* __restrict__ W1,
                 const float* __restrict__ W2, const float* __restrict__ W3,
                 f16* __restrict__ T0, f16* __restrict__ T1,
                 f16* __restrict__ T2, f16* __restrict__ T3)
{
    const int z = blockIdx.z;
    if (z == 4) {
        const int bid = blockIdx.y * 32 + blockIdx.x;
#pragma unroll
        for (int i = 0; i < 4; ++i) {
            const int off = bid * 4096 + i * 1024 + threadIdx.x * 4;
            const float4 v = *(const float4*)(x + off);
            union { int i2[2]; f16x4 h; } o;
            o.i2[0] = pk2(v.x, v.y);
            o.i2[1] = pk2(v.z, v.w);
            *(f16x4*)(xb + off) = o.h;
        }
        return;
    }
    const float* W = (z == 0) ? W0 : (z == 1) ? W1 : (z == 2) ? W2 : W3;
    f16*         Wt = (z == 0) ? T0 : (z == 1) ? T1 : (z == 2) ? T2 : T3;

    __shared__ float T[32][33];
    const int t = threadIdx.x;
    const int r = t >> 3, c4 = (t & 7) * 4;
    const int bi = blockIdx.x * 32, bj = blockIdx.y * 32;
    const float4 v = *(const float4*)(W + (size_t)(bi + r) * 1024 + bj + c4);
    T[r][c4 + 0] = v.x; T[r][c4 + 1] = v.y; T[r][c4 + 2] = v.z; T[r][c4 + 3] = v.w;
    __syncthreads();
    f16x4 o = {(f16)T[c4 + 0][r], (f16)T[c4 + 1][r], (f16)T[c4 + 2][r], (f16)T[c4 + 3][r]};
    *(f16x4*)(Wt + (size_t)(bj + r) * 1024 + bi + c4) = o;
}

// ---------------------------------------------------------------------------
// MFMA GEMM, round 16: staging via global_load_lds dwordx4 (m97 structure,
// m151: +35% over reg-staging at this tile). LDS content is bit-identical
// to the old reg-staged version: linear dest + source-side swizzle
// (col group sc ^ (srow&3)), so fragment reads are untouched.
//   QKV:     <128,128,4> -> 512 thr, 8 waves, 768 blocks = 3/CU.
//   outproj: < 64,128,2> -> 256 thr, 4 waves, 512 blocks = 2/CU.
// epi: 0 = fp32 [M,N]; 1 = l2norm f16 [b,h,s,d]; 2 = f16 [b,h,d,s].
// ---------------------------------------------------------------------------
template<int BM, int BN, int WM>
__global__ __launch_bounds__(WM * 128, 3)
void gemm_f16(const f16* __restrict__ A,
              const f16* __restrict__ B0, const f16* __restrict__ B1, const f16* __restrict__ B2,
              const float* __restrict__ bi0, const float* __restrict__ bi1, const float* __restrict__ bi2,
              void* __restrict__ o0, void* __restrict__ o1, void* __restrict__ o2,
              int e0, int e1, int e2)
{
    constexpr int NT    = WM * 128;
    constexpr int SR    = NT / 4;          // rows staged per slot
    constexpr int ASL   = BM / SR;
    constexpr int BSL   = BN / SR;
    constexpr int ABUF  = BM * 32;
    constexpr int BBUF  = BN * 32;
    constexpr int WROWS = BM / WM;
    constexpr int MT    = WROWS / 16;
    constexpr int HALVES = BN / 128;       // 128-col output halves in epi 1/2
    constexpr int SCH    = 2048 / NT;      // LDS-drain iters per half
    __shared__ __align__(16) char lds[2 * (ABUF + BBUF) * 2];
    f16* As = (f16*)lds;
    f16* Bs = (f16*)lds + 2 * ABUF;

    const int z = blockIdx.z;
    const f16*   Bt   = (z == 0) ? B0  : (z == 1) ? B1  : B2;
    const float* bias = (z == 0) ? bi0 : (z == 1) ? bi1 : bi2;
    void*        Cout = (z == 0) ? o0  : (z == 1) ? o1  : o2;
    const int    epi  = (z == 0) ? e0  : (z == 1) ? e1  : e2;

    const int tid  = threadIdx.x;
    const int lane = tid & 63;
    const int w    = tid >> 6;
    const int cl   = lane & 15;
    const int quad = lane >> 4;
    const int wm = w % WM, wn = w / WM;    // WN = 2
    const int bm = blockIdx.x * BM, bn = blockIdx.y * BN;
    const int wmoff = wm * WROWS;

    const int srow = tid >> 2;
    const int sc   = tid & 3;
    const int scg  = (sc ^ (srow & 3)) * 8;     // pre-swizzled SOURCE col group
    const f16* gA = A  + (size_t)(bm + srow) * 1024 + scg;
    const f16* gB = Bt + (size_t)(bn + srow) * 1024 + scg;
    f16* lA[ASL]; f16* lB[BSL];
#pragma unroll
    for (int i = 0; i < ASL; ++i) lA[i] = As + (srow + i * SR) * 32 + sc * 8;
#pragma unroll
    for (int i = 0; i < BSL; ++i) lB[i] = Bs + (srow + i * SR) * 32 + sc * 8;

    f32x4 acc[MT][4];
#pragma unroll
    for (int i = 0; i < MT; ++i)
#pragma unroll
        for (int j = 0; j < 4; ++j) acc[i][j] = (f32x4){0.f, 0.f, 0.f, 0.f};

    // prologue: stage k=0 into buf 0
#pragma unroll
    for (int i = 0; i < ASL; ++i) gload16(gA + (size_t)i * SR * 1024, lA[i]);
#pragma unroll
    for (int i = 0; i < BSL; ++i) gload16(gB + (size_t)i * SR * 1024, lB[i]);
    __syncthreads();

    const int fsw = (quad ^ (cl & 3)) * 8;

    for (int it = 0; it < 32; ++it) {
        const int buf = it & 1, nb = buf ^ 1;
        if (it < 31) {                      // issue next-tile loads (async)
            const int kn = (it + 1) * 32;
#pragma unroll
            for (int i = 0; i < ASL; ++i)
                gload16(gA + (size_t)i * SR * 1024 + kn, lA[i] + nb * ABUF);
#pragma unroll
            for (int i = 0; i < BSL; ++i)
                gload16(gB + (size_t)i * SR * 1024 + kn, lB[i] + nb * BBUF);
        }
        f16x8 af[MT], bf[4];
#pragma unroll
        for (int mt = 0; mt < MT; ++mt)
            af[mt] = *(const f16x8*)(&As[buf * ABUF + (wmoff + mt * 16 + cl) * 32 + fsw]);
#pragma unroll
        for (int nt = 0; nt < 4; ++nt)
            bf[nt] = *(const f16x8*)(&Bs[buf * BBUF + (wn * 64 + nt * 16 + cl) * 32 + fsw]);
#pragma unroll
        for (int mt = 0; mt < MT; ++mt)
#pragma unroll
            for (int nt = 0; nt < 4; ++nt)
                acc[mt][nt] = __builtin_amdgcn_mfma_f32_16x16x32_f16(af[mt], bf[nt], acc[mt][nt], 0, 0, 0);
        __syncthreads();                    // drains vmem (next buf ready) + lgkm
    }

    float bcol[4];
#pragma unroll
    for (int nt = 0; nt < 4; ++nt) bcol[nt] = bias[bn + wn * 64 + nt * 16 + cl];
#pragma unroll
    for (int mt = 0; mt < MT; ++mt)
#pragma unroll
        for (int nt = 0; nt < 4; ++nt)
#pragma unroll
            for (int rg = 0; rg < 4; ++rg) acc[mt][nt][rg] += bcol[nt];

    const int b_idx = bm >> 11, sl0 = bm & (SEQ - 1), h0 = bn >> 6;

    if (epi == 0) {
        float* C = (float*)Cout;
#pragma unroll
        for (int mt = 0; mt < MT; ++mt)
#pragma unroll
            for (int rg = 0; rg < 4; ++rg) {
                const int row = bm + wmoff + mt * 16 + quad * 4 + rg;
#pragma unroll
                for (int nt = 0; nt < 4; ++nt)
                    C[(size_t)row * EDIM + bn + wn * 64 + nt * 16 + cl] = acc[mt][nt][rg];
            }
    } else if (epi == 1) {                // l2norm -> f16 [b,h,s,d]
        if constexpr (BM == 128) {
        f16* C = (f16*)Cout;
        f16* S = (f16*)lds;
#pragma unroll
        for (int h = 0; h < HALVES; ++h) {
            __syncthreads();
            if ((wn >> 1) == h) {
#pragma unroll
                for (int mt = 0; mt < MT; ++mt)
#pragma unroll
                    for (int rg = 0; rg < 4; ++rg) {
                        float ss = 0.f;
#pragma unroll
                        for (int nt = 0; nt < 4; ++nt) ss += acc[mt][nt][rg] * acc[mt][nt][rg];
                        ss += __shfl_xor(ss, 1); ss += __shfl_xor(ss, 2);
                        ss += __shfl_xor(ss, 4); ss += __shfl_xor(ss, 8);
                        const float inv = 1.0f / (sqrtf(ss) + 1e-8f);
                        const int row = wmoff + mt * 16 + quad * 4 + rg;
#pragma unroll
                        for (int nt = 0; nt < 4; ++nt) {
                            const int colh = (wn & 1) * 64 + nt * 16 + cl;
                            S[row * 128 + (((colh >> 3) ^ (row & 15)) * 8) + (colh & 7)] =
                                (f16)(acc[mt][nt][rg] * inv);
                        }
                    }
            }
            __syncthreads();
#pragma unroll
            for (int i = 0; i < SCH; ++i) {
                const int c = tid + i * NT;
                const int s = c >> 4, gi = c & 15;
                f16x8 v = *(const f16x8*)(&S[s * 128 + ((gi ^ (s & 15)) * 8)]);
                const int head = h0 + h * 2 + (gi >> 3), d8 = (gi & 7) * 8;
                *(f16x8*)(C + ((size_t)(b_idx * NH + head) * SEQ + sl0 + s) * HD + d8) = v;
            }
        }
        }
    } else {                              // epi==2: f16 transposed [b,h,d,s]
        if constexpr (BM == 128) {
        f16* C = (f16*)Cout;
        f16* S = (f16*)lds;
#pragma unroll
        for (int h = 0; h < HALVES; ++h) {
            __syncthreads();
            if ((wn >> 1) == h) {
#pragma unroll
                for (int mt = 0; mt < MT; ++mt) {
                    const int s0 = wmoff + mt * 16 + quad * 4;
#pragma unroll
                    for (int nt = 0; nt < 4; ++nt) {
                        const int colh = (wn & 1) * 64 + nt * 16 + cl;
                        f16x4 o = {(f16)acc[mt][nt][0], (f16)acc[mt][nt][1],
                                   (f16)acc[mt][nt][2], (f16)acc[mt][nt][3]};
                        *(f16x4*)(&S[colh * 128 + (((s0 >> 3) ^ (colh & 15)) * 8) + (s0 & 7)]) = o;
                    }
                }
            }
            __syncthreads();
#pragma unroll
            for (int i = 0; i < SCH; ++i) {
                const int c = tid + i * NT;
                const int colh = c >> 4, gi = c & 15;
                f16x8 v = *(const f16x8*)(&S[colh * 128 + ((gi ^ (colh & 15)) * 8)]);
                const int head = h0 + h * 2 + (colh >> 6), d = colh & 63;
                *(f16x8*)(C + ((size_t)(b_idx * NH + head) * HD + d) * SEQ + sl0 + gi * 8) = v;
            }
        }
        }
    }
}

// ---------------------------------------------------------------------------
// Yat attention: VERBATIM round-0/1 kernel (verified passing 4x, 59.2-61.5us).
// r5's KVBLK=128 + packed-asm variant gave nondeterministic corruption;
// reverted wholesale (post-mortem: interaction hazard, not localizable).
// 512 threads (8 waves = 4 wm x 2 wk), 128-q tile, 64-k tiles register-staged
// + dbuf (1 barrier/iter, lgkm drain only). LDS 48 KB.
// ---------------------------------------------------------------------------
__global__ __launch_bounds__(512, 4)
void yat_attn(const f16* __restrict__ Qh, const f16* __restrict__ Kh,
              const f16* __restrict__ Vt, f16* __restrict__ AO)
{
    __shared__ __align__(16) char lds[49152];
    f16* Qs = (f16*)lds;                    // 128 x 64
    f16* KB = (f16*)(lds + 16384);          // 2 bufs x 4096 f16
    f16* VB = (f16*)(lds + 32768);          // 2 bufs x 4096 f16

    const int tid  = threadIdx.x;
    const int lane = tid & 63;
    const int w    = tid >> 6;
    const int cl   = lane & 15;
    const int quad = lane >> 4;
    const int wm = w & 3;                   // q quarter (32 q)
    const int wk = w >> 2;                  // k half (32 k)
    const int q0 = blockIdx.x * 128;
    const int bh = blockIdx.y;

    const f16* Qg = Qh + (size_t)bh * SEQ * HD;
    const f16* Kg = Kh + (size_t)bh * SEQ * HD;
    const f16* Vg = Vt + (size_t)bh * HD * SEQ;

    const int rkv = tid >> 3;               // 0..63
    const int gkv = tid & 7;
    const f16* gK = Kg + (size_t)rkv * HD + gkv * 8;
    const f16* gV = Vg + (size_t)rkv * SEQ + gkv * 8;
    const int lkOff = rkv * 64 + ((gkv ^ (rkv & 7)) * 8);

    f16x8 kr = *(const f16x8*)(gK);
    f16x8 vr = *(const f16x8*)(gV);

#pragma unroll
    for (int i = 0; i < 2; ++i) {
        const int s0 = tid + i * 512;
        const int row = s0 >> 3, g = s0 & 7;
        f16x8 v = *(const f16x8*)(Qg + (size_t)(q0 + row) * HD + g * 8);
        *(f16x8*)(&Qs[row * 64 + ((g ^ (row & 7)) * 8)]) = v;
    }
    __syncthreads();
    f16x8 qf[2][2];
#pragma unroll
    for (int qt = 0; qt < 2; ++qt)
#pragma unroll
        for (int kb = 0; kb < 2; ++kb)
            qf[qt][kb] = *(const f16x8*)(&Qs[(wm * 32 + qt * 16 + cl) * 64 +
                                             ((kb * 4 + quad) ^ (cl & 7)) * 8]);

    f32x4 O[2][4];
    float rs[2] = {0.f, 0.f};
#pragma unroll
    for (int i = 0; i < 2; ++i)
#pragma unroll
        for (int j = 0; j < 4; ++j) O[i][j] = (f32x4){0.f, 0.f, 0.f, 0.f};

    for (int t = 0; t < 32; ++t) {
        const int buf = t & 1;
        *(f16x8*)(&KB[buf * 4096 + lkOff]) = kr;
        *(f16x8*)(&VB[buf * 4096 + lkOff]) = vr;
        if (t < 31) {
            kr = *(const f16x8*)(gK + (size_t)(t + 1) * 64 * HD);
            vr = *(const f16x8*)(gV + (t + 1) * 64);
        }
        __syncthreads();                    // lgkm drain; next loads in flight

        const f16* Ks = KB + buf * 4096;
        const f16* Vs = VB + buf * 4096;

        // ---- S^T (32k x 32q) = K.Q^T, K=32 MFMAs ----
        f32x4 s[2][2];
#pragma unroll
        for (int kt = 0; kt < 2; ++kt)
#pragma unroll
            for (int qt = 0; qt < 2; ++qt) s[kt][qt] = (f32x4){0.f, 0.f, 0.f, 0.f};
#pragma unroll
        for (int kb = 0; kb < 2; ++kb) {
            const int sw = ((kb * 4 + quad) ^ (cl & 7)) * 8;
            f16x8 af0 = *(const f16x8*)(&Ks[(wk * 32 +  0 + cl) * 64 + sw]);
            f16x8 af1 = *(const f16x8*)(&Ks[(wk * 32 + 16 + cl) * 64 + sw]);
#pragma unroll
            for (int qt = 0; qt < 2; ++qt) {
                s[0][qt] = __builtin_amdgcn_mfma_f32_16x16x32_f16(af0, qf[qt][kb], s[0][qt], 0, 0, 0);
                s[1][qt] = __builtin_amdgcn_mfma_f32_16x16x32_f16(af1, qf[qt][kb], s[1][qt], 0, 0, 0);
            }
        }

        // ---- yat scores p = 4.41*rcp(u) + u - 4.2, u = 1.1 - d ----
        // packed pairs ARE the 16x16x16 A-fragments (k = quad*4 + i)
        f16x4 pa16[2][2];
#pragma unroll
        for (int kt = 0; kt < 2; ++kt)
#pragma unroll
            for (int qt = 0; qt < 2; ++qt) {
                float p[4];
#pragma unroll
                for (int rg = 0; rg < 4; ++rg) {
                    const float u = (1.0f + YAT_EPS) - s[kt][qt][rg];
                    p[rg] = fmaf(4.41f, __builtin_amdgcn_rcpf(u), u - 4.2f);
                    rs[qt] += p[rg];
                }
                union { int i2[2]; f16x4 h; } pk_;
                pk_.i2[0] = pk2(p[0], p[1]);
                pk_.i2[1] = pk2(p[2], p[3]);
                pa16[kt][qt] = pk_.h;
            }

        // ---- O += P.V via 16x16x16 MFMAs (k window: wk*32 + kt*16) ----
#pragma unroll
        for (int kt = 0; kt < 2; ++kt)
#pragma unroll
            for (int dn = 0; dn < 4; ++dn) {
                const int row = dn * 16 + cl;
                const int g = wk * 4 + kt * 2 + (quad >> 1);
                f16x4 vb = *(const f16x4*)(&Vs[row * 64 + ((g ^ (row & 7)) * 8) + (quad & 1) * 4]);
#pragma unroll
                for (int qt = 0; qt < 2; ++qt)
                    O[qt][dn] = __builtin_amdgcn_mfma_f32_16x16x16f16(pa16[kt][qt], vb, O[qt][dn], 0, 0, 0);
            }
    }

    // ---- epilogue: cross-wk reduce rs and O, normalize, store ----
    __syncthreads();
    float* rs_s = (float*)lds;
    float* Ox   = (float*)(lds + 1024);

#pragma unroll
    for (int qt = 0; qt < 2; ++qt) {
        float t = rs[qt];
        t += __shfl_xor(t, 16);
        t += __shfl_xor(t, 32);
        if (quad == 0) rs_s[wk * 128 + wm * 32 + qt * 16 + cl] = t;
    }
    if (wk == 1) {
#pragma unroll
        for (int qt = 0; qt < 2; ++qt)
#pragma unroll
            for (int dn = 0; dn < 4; ++dn)
#pragma unroll
                for (int rg = 0; rg < 4; ++rg)
                    Ox[(wm * 32 + qt * 16 + quad * 4 + rg) * 64 + dn * 16 + cl] = O[qt][dn][rg];
    }
    __syncthreads();
    if (wk == 0) {
        const int b = bh >> 4, h = bh & 15;
#pragma unroll
        for (int qt = 0; qt < 2; ++qt)
#pragma unroll
            for (int rg = 0; rg < 4; ++rg) {
                const int ql = wm * 32 + qt * 16 + quad * 4 + rg;
                const float tot = rs_s[ql] + rs_s[128 + ql];
                const float inv = 1.0f / (tot + 1e-6f);
                const size_t rowoff = ((size_t)b * SEQ + q0 + ql) * EDIM + h * 64;
#pragma unroll
                for (int dn = 0; dn < 4; ++dn)
                    AO[rowoff + dn * 16 + cl] =
                        (f16)((O[qt][dn][rg] + Ox[ql * 64 + dn * 16 + cl]) * inv);
            }
    }
}

// ---------------------------------------------------------------------------
extern "C" void kernel_launch(void* const* d_in, const int* in_sizes, int n_in,
                              void* d_out, int out_size, void* d_ws, size_t ws_size,
                              hipStream_t stream)
{
    const float* x  = (const float*)d_in[0];
    const float* Wq = (const float*)d_in[1];
    const float* bq = (const float*)d_in[2];
    const float* Wk = (const float*)d_in[3];
    const float* bk = (const float*)d_in[4];
    const float* Wv = (const float*)d_in[5];
    const float* bv = (const float*)d_in[6];
    const float* Wo = (const float*)d_in[7];
    const float* bo = (const float*)d_in[8];

    char* p = (char*)d_ws;
    f16* xb  = (f16*)p;                 p += (size_t)NROW * EDIM * 2;   // 8 MB
    f16* Wqt = (f16*)p;                 p += (size_t)EDIM * EDIM * 2;   // 2 MB
    f16* Wkt = (f16*)p;                 p += (size_t)EDIM * EDIM * 2;
    f16* Wvt = (f16*)p;                 p += (size_t)EDIM * EDIM * 2;
    f16* Wot = (f16*)p;                 p += (size_t)EDIM * EDIM * 2;
    f16* Qhb = (f16*)p;                 p += (size_t)NROW * EDIM * 2;   // [b,h,s,d]
    f16* Khb = (f16*)p;                 p += (size_t)NROW * EDIM * 2;
    f16* Vtb = (f16*)p;                 p += (size_t)NROW * EDIM * 2;   // [b,h,d,s]
    f16* AOb = (f16*)p;                 p += (size_t)NROW * EDIM * 2;   // [b,s,e]

    // prep: weight transposes (z 0..3) + x cast (z 4) in one launch
    prep_kernel<<<dim3(32, 32, 5), 256, 0, stream>>>(x, xb, Wq, Wk, Wv, Wo,
                                                     Wqt, Wkt, Wvt, Wot);

    // fused Q/K/V projections: 128x128 tiles, 8 waves -> 768 blocks
    gemm_f16<128, 128, 4><<<dim3(NROW / 128, EDIM / 128, 3), 512, 0, stream>>>(
        xb, Wqt, Wkt, Wvt, bq, bk, bv, Qhb, Khb, Vtb, 1, 1, 2);

    // attention: 128-q tiles, 64-k tiles -> 512 blocks (verified r0/r1 kernel)
    yat_attn<<<dim3(SEQ / 128, BATCH * NH), 512, 0, stream>>>(Qhb, Khb, Vtb, AOb);

    // output projection: 64x128 tiles -> 512 blocks
    gemm_f16<64, 128, 2><<<dim3(NROW / 64, EDIM / 128, 1), 256, 0, stream>>>(
        AOb, Wot, Wot, Wot, bo, bo, bo, d_out, d_out, d_out, 0, 0, 0);
}